// Round 1
// 319.459 us; speedup vs baseline: 1.0433x; 1.0433x over previous
//
#include <hip/hip_runtime.h>
#include <math.h>

#define NB 256
#define NV 32000
#define ND 1024
#define NT 64

// ---- GEMM config ----
#define GN 64
#define ASTR 56            // padded row stride (f16) for A lds tile
#define NKB 64             // 1024/16 k-blocks
#define ASLAB (256 * ASTR) // f16 per k-block slab = 14336 (28672 B)
#define NGBLK (NV / GN)    // 500
#define INV2048F 4.8828125e-4f

// ---- sampling config ----
#define NBIN 1024
#define FIX2 4294967296.0   // 2^32
#define PACK1 (1ull << 48)
#define SMASK ((1ull << 48) - 1ull)

typedef _Float16 f16x8 __attribute__((ext_vector_type(8)));
typedef _Float16 f16x4 __attribute__((ext_vector_type(4)));
typedef float f32x16 __attribute__((ext_vector_type(16)));
typedef __attribute__((address_space(3))) void lds_void;
typedef __attribute__((address_space(1))) void glb_void;

struct RowP2 {
  unsigned long long basePack;  // (count<<48 | sumfix) of elements strictly above range
  unsigned long long toppZfix;
  unsigned pfx;                 // accumulated bin path (10 bits per resolved level)
  int ktop;
  float invZ;
  unsigned ustar;
  int m;
  int cEq;
};  // 40 B

__device__ __forceinline__ unsigned mono_enc(float f) {
  unsigned u = __float_as_uint(f);
  return (u & 0x80000000u) ? ~u : (u | 0x80000000u);
}
__device__ __forceinline__ float mono_dec(unsigned u) {
  return (u & 0x80000000u) ? __uint_as_float(u & 0x7FFFFFFFu) : __uint_as_float(~u);
}

// ---------------- convert A: LDS-staged slab build, coalesced output ----------------
__global__ __launch_bounds__(256) void convert_A(const float* __restrict__ hidden,
                                                 _Float16* __restrict__ A3) {
  const int kb = blockIdx.x, t = threadIdx.x;
  __shared__ _Float16 slab[ASLAB];  // 28672 B
#pragma unroll
  for (int it = 0; it < 4; it++) {
    const int m = it * 64 + (t >> 2);
    const int k4 = (t & 3) * 4;
    float4 a4 = *(const float4*)(hidden + (size_t)m * ND + kb * 16 + k4);
    _Float16* base = slab + m * ASTR;
    float v[4] = {a4.x, a4.y, a4.z, a4.w};
#pragma unroll
    for (int q = 0; q < 4; q++) {
      const _Float16 h = (_Float16)v[q];
      const _Float16 l2 = (_Float16)((v[q] - (float)h) * 2048.0f);
      const int kk = k4 + q;
      base[kk] = h;
      base[16 + 2 * kk] = h;
      base[17 + 2 * kk] = l2;
    }
  }
  __syncthreads();
  const uint4* s = (const uint4*)slab;
  uint4* g = (uint4*)(A3 + (size_t)kb * ASLAB);
#pragma unroll
  for (int i = 0; i < 7; i++) g[i * 256 + t] = s[i * 256 + t];
}

// ---------------- MFMA f16-split GEMM, software-pipelined ----------------
// Pipeline invariants (per wave, VMEM queue oldest->newest):
//   entering iter k (k>=1): [ A_k x7 (global_load_lds -> Als[k&1]), B_{k+1} (float4 reg) ] = 8
//   iter k issues: A_{k+1} x7, then B_{k+2}  -> 16 outstanding
//   vmcnt(9)  drains A_k x7   (Als[k&1] ready for MY ds_reads; A is wave-private, no barrier needed)
//   vmcnt(8)  drains B_{k+1}  (convert + ds_write to Bls[(k+1)&1])
//   lgkmcnt(0); s_barrier     (publish Bls only; A loads stay in flight across the barrier)
__global__ __launch_bounds__(256, 2) void gemm_f16s(
    const float* __restrict__ Bm, const _Float16* __restrict__ A3,
    const float* __restrict__ temp, unsigned* __restrict__ rowmax,
    float* __restrict__ C) {
  __shared__ _Float16 Als[2][ASLAB];      // 57,344 B
  __shared__ _Float16 Bls[2][GN * ASTR];  // 14,336 B
  __shared__ float s_invT[256];
  __shared__ unsigned s_pm[256];

  const int t = threadIdx.x;
  const int l = t & 63, w = t >> 6;
  const int n0 = blockIdx.x * GN;
  s_invT[t] = 1.0f / temp[t];
  s_pm[t] = 0u;

  f32x16 accA[2][2] = {};
  f32x16 accB[2][2] = {};

  const int bn = t >> 2, bk4 = (t & 3) * 4;
  const int l31 = l & 31, lh = l >> 5;
  const int ka = lh * 8;
  const int mb = w * 64;

  const float* browp = Bm + (size_t)(n0 + bn) * ND + bk4;
  const char* gaBase = (const char*)A3 + (w * 7) * 1024 + l * 16;
  char* laB0 = (char*)&Als[0][0] + (w * 7) * 1024;
  char* laB1 = (char*)&Als[1][0] + (w * 7) * 1024;

#define ISSUE_A(kbn, LA)                                                        \
  do {                                                                          \
    const char* ga_ = gaBase + (size_t)(kbn) * (ASLAB * 2);                     \
    _Pragma("unroll") for (int i_ = 0; i_ < 7; i_++)                            \
        __builtin_amdgcn_global_load_lds((const glb_void*)(ga_ + i_ * 1024),    \
                                         (lds_void*)((LA) + i_ * 1024), 16, 0,  \
                                         0);                                    \
  } while (0)

#define BCONV(BV, DST)                                                          \
  do {                                                                          \
    const _Float16 h0_ = (_Float16)(BV).x, h1_ = (_Float16)(BV).y,              \
                   h2_ = (_Float16)(BV).z, h3_ = (_Float16)(BV).w;              \
    const _Float16 q0_ = (_Float16)(((BV).x - (float)h0_) * 2048.0f);           \
    const _Float16 q1_ = (_Float16)(((BV).y - (float)h1_) * 2048.0f);           \
    const _Float16 q2_ = (_Float16)(((BV).z - (float)h2_) * 2048.0f);           \
    const _Float16 q3_ = (_Float16)(((BV).w - (float)h3_) * 2048.0f);           \
    _Float16* prow_ = (DST) + bn * ASTR;                                        \
    *(f16x4*)(prow_ + bk4) = (f16x4){h0_, h1_, h2_, h3_};                       \
    *(f16x8*)(prow_ + 16 + 2 * bk4) =                                           \
        (f16x8){q0_, h0_, q1_, h1_, q2_, h2_, q3_, h3_};                        \
  } while (0)

#define COMPUTE(CUR)                                                                       \
  do {                                                                                     \
    const _Float16* Ap_ = &Als[CUR][0] + (size_t)(mb + l31) * ASTR + ka;                   \
    const _Float16* Bp_ = &Bls[CUR][0] + (size_t)l31 * ASTR + ka;                          \
    f16x8 a0_ = *(const f16x8*)(Ap_);                                                      \
    f16x8 a1_ = *(const f16x8*)(Ap_ + 32 * ASTR);                                          \
    f16x8 b0_ = *(const f16x8*)(Bp_);                                                      \
    f16x8 b1_ = *(const f16x8*)(Bp_ + 32 * ASTR);                                          \
    accA[0][0] = __builtin_amdgcn_mfma_f32_32x32x16_f16(a0_, b0_, accA[0][0], 0, 0, 0);    \
    accA[0][1] = __builtin_amdgcn_mfma_f32_32x32x16_f16(a0_, b1_, accA[0][1], 0, 0, 0);    \
    accA[1][0] = __builtin_amdgcn_mfma_f32_32x32x16_f16(a1_, b0_, accA[1][0], 0, 0, 0);    \
    accA[1][1] = __builtin_amdgcn_mfma_f32_32x32x16_f16(a1_, b1_, accA[1][1], 0, 0, 0);    \
    _Pragma("unroll") for (int s_ = 0; s_ < 2; s_++) {                                     \
      const int off_ = 16 + s_ * 16;                                                       \
      f16x8 c0_ = *(const f16x8*)(Ap_ + off_);                                             \
      f16x8 c1_ = *(const f16x8*)(Ap_ + 32 * ASTR + off_);                                 \
      f16x8 d0_ = *(const f16x8*)(Bp_ + off_);                                             \
      f16x8 d1_ = *(const f16x8*)(Bp_ + 32 * ASTR + off_);                                 \
      accB[0][0] = __builtin_amdgcn_mfma_f32_32x32x16_f16(c0_, d0_, accB[0][0], 0, 0, 0);  \
      accB[0][1] = __builtin_amdgcn_mfma_f32_32x32x16_f16(c0_, d1_, accB[0][1], 0, 0, 0);  \
      accB[1][0] = __builtin_amdgcn_mfma_f32_32x32x16_f16(c1_, d0_, accB[1][0], 0, 0, 0);  \
      accB[1][1] = __builtin_amdgcn_mfma_f32_32x32x16_f16(c1_, d1_, accB[1][1], 0, 0, 0);  \
    }                                                                                      \
  } while (0)

  // ---- prologue: stage tile 0 into buf0; leave B[1] in flight ----
  ISSUE_A(0, laB0);
  __builtin_amdgcn_sched_barrier(0);
  float4 bv0 = *(const float4*)(browp);
  __builtin_amdgcn_sched_barrier(0);
  float4 bvA = *(const float4*)(browp + 16);  // B[1]
  __builtin_amdgcn_sched_barrier(0);
  asm volatile("s_waitcnt vmcnt(1)" ::: "memory");  // A0 x7 + B0 done; B1 in flight
  BCONV(bv0, &Bls[0][0]);
  asm volatile("s_waitcnt lgkmcnt(0)\ns_barrier" ::: "memory");

  float4 bvB;
  // ---- main loop: tiles 0..61, manually unrolled x2 for static buffer parity ----
  for (int kb = 0; kb < 62; kb += 2) {
    // even tile kb (cur=0): consume bvA=B[kb+1], prefetch A[kb+1], B[kb+2]
    ISSUE_A(kb + 1, laB1);
    __builtin_amdgcn_sched_barrier(0);
    bvB = *(const float4*)(browp + (size_t)(kb + 2) * 16);
    __builtin_amdgcn_sched_barrier(0);
    asm volatile("s_waitcnt vmcnt(9)" ::: "memory");
    COMPUTE(0);
    __builtin_amdgcn_sched_barrier(0);
    asm volatile("s_waitcnt vmcnt(8)" ::: "memory");
    BCONV(bvA, &Bls[1][0]);
    asm volatile("s_waitcnt lgkmcnt(0)\ns_barrier" ::: "memory");

    // odd tile kb+1 (cur=1): consume bvB=B[kb+2], prefetch A[kb+2], B[kb+3]
    ISSUE_A(kb + 2, laB0);
    __builtin_amdgcn_sched_barrier(0);
    bvA = *(const float4*)(browp + (size_t)(kb + 3) * 16);
    __builtin_amdgcn_sched_barrier(0);
    asm volatile("s_waitcnt vmcnt(9)" ::: "memory");
    COMPUTE(1);
    __builtin_amdgcn_sched_barrier(0);
    asm volatile("s_waitcnt vmcnt(8)" ::: "memory");
    BCONV(bvB, &Bls[0][0]);
    asm volatile("s_waitcnt lgkmcnt(0)\ns_barrier" ::: "memory");
  }

  // ---- tile 62 (cur=0): entering queue = [A62 x7, B63]; no new B issue ----
  ISSUE_A(63, laB1);
  __builtin_amdgcn_sched_barrier(0);
  asm volatile("s_waitcnt vmcnt(8)" ::: "memory");  // drain A62 x7
  COMPUTE(0);
  __builtin_amdgcn_sched_barrier(0);
  asm volatile("s_waitcnt vmcnt(7)" ::: "memory");  // drain B63
  BCONV(bvA, &Bls[1][0]);
  asm volatile("s_waitcnt lgkmcnt(0)\ns_barrier" ::: "memory");

  // ---- tile 63 (cur=1) ----
  asm volatile("s_waitcnt vmcnt(0)" ::: "memory");  // drain A63 x7
  COMPUTE(1);

#undef ISSUE_A
#undef BCONV
#undef COMPUTE

#pragma unroll
  for (int mi = 0; mi < 2; mi++) {
#pragma unroll
    for (int r = 0; r < 16; r++) {
      const int row = mb + mi * 32 + (r & 3) + 8 * (r >> 2) + 4 * lh;
      const float it = s_invT[row];
      float v0 = (accA[mi][0][r] + accB[mi][0][r] * INV2048F) * it;
      float v1 = (accA[mi][1][r] + accB[mi][1][r] * INV2048F) * it;
      C[(size_t)row * NV + n0 + l31] = v0;
      C[(size_t)row * NV + n0 + 32 + l31] = v1;
      float mx = fmaxf(v0, v1);
#pragma unroll
      for (int o = 1; o < 32; o <<= 1) mx = fmaxf(mx, __shfl_xor(mx, o));
      if (l31 == 0) atomicMax(&s_pm[row], mono_enc(mx));
    }
  }
  __syncthreads();
  atomicMax(&rowmax[t], s_pm[t]);
}

// ---------------- S0: Mrow decode + apply penalties in-place to x ----------------
__global__ __launch_bounds__(64) void s0_prep(
    const unsigned* __restrict__ rowmax, const int* __restrict__ toks,
    const float* __restrict__ pres, const float* __restrict__ freq,
    const float* __restrict__ temp, float* __restrict__ Mrow,
    float* __restrict__ buf) {
  const int b = blockIdx.x, t = threadIdx.x;
  __shared__ int s_tok[NT];
  s_tok[t] = toks[b * NT + t];
  __syncthreads();
  const int tk = s_tok[t];
  bool first = true; int cnt = 0;
  for (int j = 0; j < NT; j++)
    if (s_tok[j] == tk) { if (j < t) first = false; cnt++; }
  if (first)
    buf[(size_t)b * NV + tk] -= (freq[b] * (float)cnt + pres[b]) / temp[b];
  if (t == 0) Mrow[b] = mono_dec(rowmax[b]);
}

// ---------------- H0: e = exp(x-M) written in place + level-0 histogram (k>>20) ------
__global__ __launch_bounds__(256) void h_l0(
    float* __restrict__ buf, const float* __restrict__ Mrow,
    unsigned long long* __restrict__ histP) {
  const int b = blockIdx.x >> 3, sl = blockIdx.x & 7, t = threadIdx.x;
  __shared__ unsigned long long h[NBIN];
  for (int i = t; i < NBIN; i += 256) h[i] = 0ull;
  __syncthreads();
  const float M = Mrow[b];
  float* row = buf + (size_t)b * NV;
  const int base = sl * 4096;
#pragma unroll
  for (int it = 0; it < 4; it++) {
    const int idx = base + (it * 256 + t) * 4;
    if (idx < NV) {
      float4 x4 = *(const float4*)(row + idx);
      float4 e4;
      e4.x = expf(x4.x - M); e4.y = expf(x4.y - M);
      e4.z = expf(x4.z - M); e4.w = expf(x4.w - M);
      *(float4*)(row + idx) = e4;
      unsigned k;
      k = __float_as_uint(e4.x); if (k) atomicAdd(&h[k >> 20], PACK1 | (unsigned long long)(e4.x * FIX2));
      k = __float_as_uint(e4.y); if (k) atomicAdd(&h[k >> 20], PACK1 | (unsigned long long)(e4.y * FIX2));
      k = __float_as_uint(e4.z); if (k) atomicAdd(&h[k >> 20], PACK1 | (unsigned long long)(e4.z * FIX2));
      k = __float_as_uint(e4.w); if (k) atomicAdd(&h[k >> 20], PACK1 | (unsigned long long)(e4.w * FIX2));
    }
  }
  __syncthreads();
  unsigned long long* gh = histP + (size_t)b * NBIN;
  for (int i = t; i < NBIN; i += 256)
    if (h[i]) atomicAdd(&gh[i], h[i]);
}

// ---------------- H-refine: histogram restricted to current prefix range ------------
__global__ __launch_bounds__(256) void h_ref(
    const float* __restrict__ buf, const RowP2* __restrict__ params,
    unsigned long long* __restrict__ histP, int matchShift, int binShift) {
  const int b = blockIdx.x >> 3, sl = blockIdx.x & 7, t = threadIdx.x;
  __shared__ unsigned long long h[NBIN];
  for (int i = t; i < NBIN; i += 256) h[i] = 0ull;
  __syncthreads();
  const unsigned pfx = params[b].pfx;
  const float* row = buf + (size_t)b * NV;
  const int base = sl * 4096;
#pragma unroll
  for (int it = 0; it < 4; it++) {
    const int idx = base + (it * 256 + t) * 4;
    if (idx < NV) {
      float4 e4 = *(const float4*)(row + idx);
      unsigned k;
      k = __float_as_uint(e4.x); if (k && (k >> matchShift) == pfx) atomicAdd(&h[(k >> binShift) & 1023u], PACK1 | (unsigned long long)(e4.x * FIX2));
      k = __float_as_uint(e4.y); if (k && (k >> matchShift) == pfx) atomicAdd(&h[(k >> binShift) & 1023u], PACK1 | (unsigned long long)(e4.y * FIX2));
      k = __float_as_uint(e4.z); if (k && (k >> matchShift) == pfx) atomicAdd(&h[(k >> binShift) & 1023u], PACK1 | (unsigned long long)(e4.z * FIX2));
      k = __float_as_uint(e4.w); if (k && (k >> matchShift) == pfx) atomicAdd(&h[(k >> binShift) & 1023u], PACK1 | (unsigned long long)(e4.w * FIX2));
    }
  }
  __syncthreads();
  unsigned long long* gh = histP + (size_t)b * NBIN;
  for (int i = t; i < NBIN; i += 256)
    if (h[i]) atomicAdd(&gh[i], h[i]);
}

// ---------------- S2: suffix-scan bins, descend one level (also zeroes hist) --------
__global__ __launch_bounds__(256) void s2_level(
    unsigned long long* __restrict__ histP, const float* __restrict__ topp_a,
    const int* __restrict__ topk_a, RowP2* __restrict__ params, int level) {
  const int b = blockIdx.x, t = threadIdx.x;
  __shared__ unsigned long long suf[NBIN];
  __shared__ unsigned long long sc[256];
  __shared__ int s_bs;
  unsigned long long* hp = histP + (size_t)b * NBIN;
  unsigned long long v[4];
#pragma unroll
  for (int i = 0; i < 4; i++) { v[i] = hp[t * 4 + i]; hp[t * 4 + i] = 0ull; }
  if (t == 0) s_bs = 1023;
  sc[t] = v[0] + v[1] + v[2] + v[3];
  __syncthreads();
  for (int off = 1; off < 256; off <<= 1) {
    unsigned long long add = (t + off < 256) ? sc[t + off] : 0ull;
    __syncthreads();
    sc[t] += add;
    __syncthreads();
  }
  const unsigned long long totalP = sc[0];
  unsigned long long run = (t < 255) ? sc[t + 1] : 0ull;
  suf[t * 4 + 3] = run; run += v[3];
  suf[t * 4 + 2] = run; run += v[2];
  suf[t * 4 + 1] = run; run += v[1];
  suf[t * 4 + 0] = run;
  __syncthreads();

  RowP2 p;
  unsigned long long base, toppZ;
  int ktop_;
  if (level == 0) {
    ktop_ = topk_a[b];
    unsigned long long Zfix = totalP & SMASK;
    if (!Zfix) Zfix = 1ull;
    toppZ = (unsigned long long)((double)topp_a[b] * (double)Zfix);
    base = 0ull;
    p.pfx = 0; p.invZ = (float)(FIX2 / (double)Zfix);
    p.ustar = 0; p.m = 0; p.cEq = 0;
  } else {
    p = params[b];
    base = p.basePack; toppZ = p.toppZfix; ktop_ = p.ktop;
  }

#pragma unroll
  for (int i = 0; i < 4; i++) {
    const int bin = t * 4 + i;
    const unsigned long long sG = base + suf[bin];
    const bool A = ((long long)(sG >> 48) < (long long)ktop_) && ((sG & SMASK) <= toppZ);
    const unsigned long long sPfull = base + ((bin > 0) ? suf[bin - 1] : totalP);
    const bool Ap = ((long long)(sPfull >> 48) < (long long)ktop_) && ((sPfull & SMASK) <= toppZ);
    if (A && !Ap) s_bs = bin;
  }
  __syncthreads();
  if (t == 0) {
    const int bs = s_bs;
    const unsigned long long newBase = base + suf[bs];
    if (level < 2) {
      p.basePack = newBase;
      p.toppZfix = toppZ;
      p.ktop = ktop_;
      p.pfx = (level == 0) ? (unsigned)bs : ((p.pfx << 10) | (unsigned)bs);
      params[b] = p;
    } else {
      const unsigned ustar = (p.pfx << 10) | (unsigned)bs;
      const unsigned long long raw = ((bs > 0) ? suf[bs - 1] : totalP) - suf[bs];
      const int cEq = (int)(raw >> 48);
      const long long Chi = (long long)(newBase >> 48);
      const unsigned long long Shi = newBase & SMASK;
      long long m = cEq;
      const long long lim = (long long)ktop_ - Chi;
      if (lim < m) m = lim;
      const double tf = (double)__uint_as_float(ustar) * FIX2;
      const double rem = (double)(toppZ - Shi);
      const double Rd = floor(rem / tf) + 1.0;
      if (Rd < (double)m) m = (long long)Rd;
      if (m < 1) m = 1;
      p.ustar = ustar; p.m = (int)m; p.cEq = cEq;
      params[b] = p;
    }
  }
}

// ---------------- S3: final filter (sentinel −e only if ties must be ranked) --------
__global__ __launch_bounds__(256) void s3_filter(
    float* __restrict__ buf, const RowP2* __restrict__ params) {
  const int b = blockIdx.x >> 3, sl = blockIdx.x & 7, t = threadIdx.x;
  const RowP2 p = params[b];
  const unsigned ustar = p.ustar;
  const float invZ = p.invZ;
  const bool need = (p.m < p.cEq);
  float* row = buf + (size_t)b * NV;
  const int base = sl * 4096;
#pragma unroll
  for (int it = 0; it < 4; it++) {
    const int idx = base + (it * 256 + t) * 4;
    if (idx < NV) {
      float4 e4 = *(const float4*)(row + idx);
      float4 o4;
      unsigned k;
      k = __float_as_uint(e4.x);
      o4.x = (k > ustar) ? e4.x * invZ : ((k == ustar) ? (need ? -e4.x : e4.x * invZ) : 0.f);
      k = __float_as_uint(e4.y);
      o4.y = (k > ustar) ? e4.y * invZ : ((k == ustar) ? (need ? -e4.y : e4.y * invZ) : 0.f);
      k = __float_as_uint(e4.z);
      o4.z = (k > ustar) ? e4.z * invZ : ((k == ustar) ? (need ? -e4.z : e4.z * invZ) : 0.f);
      k = __float_as_uint(e4.w);
      o4.w = (k > ustar) ? e4.w * invZ : ((k == ustar) ? (need ? -e4.w : e4.w * invZ) : 0.f);
      *(float4*)(row + idx) = o4;
    }
  }
}

// ---------------- S5: rare tie-rank fixup (no-op unless m < cEq) ----------------
__global__ __launch_bounds__(256) void s5_tie(
    float* __restrict__ buf, const RowP2* __restrict__ params) {
  const int b = blockIdx.x, t = threadIdx.x;
  const RowP2 p = params[b];
  if (p.m >= p.cEq) return;
  const int m = p.m;
  const float invZ = p.invZ;
  float* row = buf + (size_t)b * NV;
  __shared__ int s_rank[256];
  const int CH = NV / 256;  // 125
  const int base = t * CH, end = base + CH;
  int myc = 0;
  for (int v = base; v < end; v++) myc += (row[v] < 0.f);
  s_rank[t] = myc;
  __syncthreads();
  for (int off = 1; off < 256; off <<= 1) {
    const int v0 = s_rank[t];
    const int vn = (t >= off) ? s_rank[t - off] : 0;
    __syncthreads();
    s_rank[t] = v0 + vn;
    __syncthreads();
  }
  int r = (t > 0) ? s_rank[t - 1] : 0;
  for (int v = base; v < end; v++) {
    const float f = row[v];
    if (f < 0.f) {
      row[v] = (r < m) ? (-f) * invZ : 0.f;
      r++;
    }
  }
}

extern "C" void kernel_launch(void* const* d_in, const int* in_sizes, int n_in,
                              void* d_out, int out_size, void* d_ws, size_t ws_size,
                              hipStream_t stream) {
  (void)in_sizes; (void)n_in; (void)out_size; (void)ws_size;
  const float* hidden = (const float*)d_in[0];
  const float* emb    = (const float*)d_in[1];
  const int*   toks   = (const int*)d_in[2];
  const float* pres   = (const float*)d_in[3];
  const float* freq   = (const float*)d_in[4];
  const float* temp   = (const float*)d_in[5];
  const float* topp   = (const float*)d_in[6];
  const int*   topk   = (const int*)d_in[7];
  float* out = (float*)d_out;

  // ws layout (total ≈ 3.95 MB)
  const size_t offA3   = 0;                       // 1,835,008 B
  const size_t offRM   = 1835008;                 // 1,024 B  (zeroed)
  const size_t offHist = offRM + 1024;            // 2,097,152 B (zeroed)
  const size_t offMr   = offHist + 2097152;       // 1,024 B
  const size_t offPar  = offMr + 1024;            // 256*40 B

  _Float16* A3 = (_Float16*)((char*)d_ws + offA3);
  unsigned* rowmax = (unsigned*)((char*)d_ws + offRM);
  unsigned long long* histP = (unsigned long long*)((char*)d_ws + offHist);
  float* Mrow = (float*)((char*)d_ws + offMr);
  RowP2* params = (RowP2*)((char*)d_ws + offPar);

  hipMemsetAsync((char*)d_ws + offRM, 0, 1024 + 2097152, stream);
  convert_A<<<NKB, 256, 0, stream>>>(hidden, A3);
  gemm_f16s<<<NGBLK, 256, 0, stream>>>(emb, A3, temp, rowmax, out);
  s0_prep<<<NB, 64, 0, stream>>>(rowmax, toks, pres, freq, temp, Mrow, out);
  h_l0<<<NB * 8, 256, 0, stream>>>(out, Mrow, histP);
  s2_level<<<NB, 256, 0, stream>>>(histP, topp, topk, params, 0);
  h_ref<<<NB * 8, 256, 0, stream>>>(out, params, histP, 20, 10);
  s2_level<<<NB, 256, 0, stream>>>(histP, topp, topk, params, 1);
  h_ref<<<NB * 8, 256, 0, stream>>>(out, params, histP, 10, 0);
  s2_level<<<NB, 256, 0, stream>>>(histP, topp, topk, params, 2);
  s3_filter<<<NB * 8, 256, 0, stream>>>(out, params);
  s5_tie<<<NB, 256, 0, stream>>>(out, params);
}